// Round 3
// baseline (16921.193 us; speedup 1.0000x reference)
//
#include <hip/hip_runtime.h>
#include <float.h>
#include <math.h>

#define DIM 2048
#define HEADS 16
#define BATCH 2
#define SEQ 2048
#define HD 128              // head dim
#define MROWS (BATCH * SEQ) // 4096

// ---------------------------------------------------------------------------
// fp32 tiled GEMM: C(MxN) = A(MxK) @ B(KxN), all row-major, dims % 128 == 0.
// 128x128 tile, BK=16, 256 threads, 8x8 micro-tile per thread. (unchanged)
// ---------------------------------------------------------------------------
__global__ __launch_bounds__(256) void gemm_f32(const float* __restrict__ A,
                                                const float* __restrict__ B,
                                                float* __restrict__ C,
                                                int M, int N, int K) {
    constexpr int GM = 128, GN = 128, GK = 16;
    __shared__ float As[GK][GM + 4];
    __shared__ float Bs[GK][GN];

    const int t = threadIdx.x;
    const int bm = blockIdx.y * GM;
    const int bn = blockIdx.x * GN;
    const int tr = t >> 4;
    const int tc = t & 15;

    const int arow0 = t >> 2;
    const int ac4   = t & 3;
    const int brow0 = t >> 5;
    const int bc4   = t & 31;

    float acc[8][8] = {};

    for (int k0 = 0; k0 < K; k0 += GK) {
#pragma unroll
        for (int ii = 0; ii < 2; ++ii) {
            const int row = arow0 + ii * 64;
            const float4 a4 = *reinterpret_cast<const float4*>(
                A + (size_t)(bm + row) * K + k0 + ac4 * 4);
            As[ac4 * 4 + 0][row] = a4.x;
            As[ac4 * 4 + 1][row] = a4.y;
            As[ac4 * 4 + 2][row] = a4.z;
            As[ac4 * 4 + 3][row] = a4.w;
        }
#pragma unroll
        for (int ii = 0; ii < 2; ++ii) {
            const int row = brow0 + ii * 8;
            *reinterpret_cast<float4*>(&Bs[row][bc4 * 4]) =
                *reinterpret_cast<const float4*>(B + (size_t)(k0 + row) * N + bn + bc4 * 4);
        }
        __syncthreads();

#pragma unroll
        for (int kk = 0; kk < GK; ++kk) {
            float a[8], b[8];
            *reinterpret_cast<float4*>(a)     = *reinterpret_cast<const float4*>(&As[kk][tr * 8]);
            *reinterpret_cast<float4*>(a + 4) = *reinterpret_cast<const float4*>(&As[kk][tr * 8 + 4]);
            *reinterpret_cast<float4*>(b)     = *reinterpret_cast<const float4*>(&Bs[kk][tc * 8]);
            *reinterpret_cast<float4*>(b + 4) = *reinterpret_cast<const float4*>(&Bs[kk][tc * 8 + 4]);
#pragma unroll
            for (int i = 0; i < 8; ++i)
#pragma unroll
                for (int jj = 0; jj < 8; ++jj)
                    acc[i][jj] = fmaf(a[i], b[jj], acc[i][jj]);
        }
        __syncthreads();
    }

#pragma unroll
    for (int i = 0; i < 8; ++i) {
        float* crow = C + (size_t)(bm + tr * 8 + i) * N + bn + tc * 8;
        *reinterpret_cast<float4*>(crow)     = make_float4(acc[i][0], acc[i][1], acc[i][2], acc[i][3]);
        *reinterpret_cast<float4*>(crow + 4) = make_float4(acc[i][4], acc[i][5], acc[i][6], acc[i][7]);
    }
}

// ---------------------------------------------------------------------------
// Flash attention, anti-causal mask (keep k > q). Restructured for occupancy:
//   QT=64 -> 1024 blocks (4/CU), LDS = 40960 B exactly (4 blocks/CU),
//   heavy-first blockIdx remap for load balance,
//   P[64][32] XOR-swizzled (kk ^ row&7) -> conflict-free, no padding,
//   phase A/B LDS reads rotated by (c+j)&3 -> 4-way conflicts down to free 2-way.
// Thread (rs=t>>3, j=t&7) owns rows {rs, rs+32} x d-cols [j*16, j*16+16).
// ---------------------------------------------------------------------------
constexpr int QT = 64;
constexpr int KT = 32;

__global__ __launch_bounds__(256, 4) void attn_f32(const float* __restrict__ Q,
                                                   const float* __restrict__ Kp,
                                                   const float* __restrict__ Vp,
                                                   float* __restrict__ Op) {
    __shared__ float Ks[KT][HD];       // 16 KB
    __shared__ float Vs[KT][HD];       // 16 KB
    __shared__ float P[QT][KT];        // 8 KB, swizzled [row][kk ^ (row&7)]

    const int t = threadIdx.x;
    const int j = t & 7;
    const int rs = t >> 3;             // 0..31
    // heavy-first remap: qRank 0 -> qi 31 (full work), then 0,1,...,30 (descending)
    const int qRank = blockIdx.x >> 5; // 0..31
    const int bh = blockIdx.x & 31;
    const int h = bh & 15;
    const int b = bh >> 4;
    const int qi = (qRank == 0) ? 31 : qRank - 1;
    const int q0 = qi * QT;
    const float scale = 0.08838834764831845f;  // 1/sqrt(128)

    const size_t base = ((size_t)b * SEQ) * DIM + (size_t)h * HD;
    const float* Qb = Q + base;
    const float* Kb = Kp + base;
    const float* Vb = Vp + base;
    float* Ob = Op + base;

    // Q fragments: 2 rows x own 16 cols
    float qf[2][16];
#pragma unroll
    for (int ri = 0; ri < 2; ++ri) {
        const float* src = Qb + (size_t)(q0 + rs + 32 * ri) * DIM + j * 16;
#pragma unroll
        for (int i = 0; i < 16; i += 4)
            *reinterpret_cast<float4*>(&qf[ri][i]) = *reinterpret_cast<const float4*>(src + i);
    }

    float m[2], l[2], o[2][16];
#pragma unroll
    for (int ri = 0; ri < 2; ++ri) {
        m[ri] = -INFINITY;
        l[ri] = 0.f;
#pragma unroll
        for (int i = 0; i < 16; ++i) o[ri][i] = 0.f;
    }

    // Skip K-tiles that are fully masked for every row of this q-tile.
    // Last q-tile (qi==31) processes everything so the fully-masked row S-1
    // degenerates to uniform 1/S exactly like the reference.
    const int ktStart = (qi == SEQ / QT - 1) ? 0 : (q0 + 1) / KT;

    for (int kt = ktStart; kt < SEQ / KT; ++kt) {
        const int k0 = kt * KT;
        // stage K/V tile: contiguous-per-wave float4 writes (conflict-free)
#pragma unroll
        for (int ii = 0; ii < 4; ++ii) {
            const int id = ii * 256 + t;
            const int kr = id >> 5;
            const int c4 = id & 31;
            *reinterpret_cast<float4*>(&Ks[kr][c4 * 4]) =
                *reinterpret_cast<const float4*>(Kb + (size_t)(k0 + kr) * DIM + c4 * 4);
            *reinterpret_cast<float4*>(&Vs[kr][c4 * 4]) =
                *reinterpret_cast<const float4*>(Vb + (size_t)(k0 + kr) * DIM + c4 * 4);
        }
        __syncthreads();

        // ---- phase A: logits + per-row tile max ----
        float mt[2] = {-INFINITY, -INFINITY};
#pragma unroll 4
        for (int kk = 0; kk < KT; ++kk) {
            float kf[16];
#pragma unroll
            for (int c = 0; c < 4; ++c) {   // rotated reads: 4-way -> 2-way (free)
                const int cc = (c + j) & 3;
                *reinterpret_cast<float4*>(&kf[cc * 4]) =
                    *reinterpret_cast<const float4*>(&Ks[kk][j * 16 + cc * 4]);
            }
            const int kg = k0 + kk;
#pragma unroll
            for (int ri = 0; ri < 2; ++ri) {
                float s = 0.f;
#pragma unroll
                for (int i = 0; i < 16; ++i) s = fmaf(qf[ri][i], kf[i], s);
                s += __shfl_xor(s, 1);
                s += __shfl_xor(s, 2);
                s += __shfl_xor(s, 4);
                const int row = rs + 32 * ri;
                const int qg = q0 + row;
                const float logit = (kg > qg) ? s * scale : -FLT_MAX;
                mt[ri] = fmaxf(mt[ri], logit);
                if (j == 0) P[row][kk ^ (rs & 7)] = logit;  // swizzled store
            }
        }
        __syncthreads();

        // ---- online-softmax rescale ----
#pragma unroll
        for (int ri = 0; ri < 2; ++ri) {
            const float mn = fmaxf(m[ri], mt[ri]);
            const float corr = __expf(m[ri] - mn);
            m[ri] = mn;
            l[ri] *= corr;
#pragma unroll
            for (int i = 0; i < 16; ++i) o[ri][i] *= corr;
        }

        // ---- phase B: P*V accumulate ----
#pragma unroll 4
        for (int kk = 0; kk < KT; ++kk) {
            float vf[16];
#pragma unroll
            for (int c = 0; c < 4; ++c) {
                const int cc = (c + j) & 3;
                *reinterpret_cast<float4*>(&vf[cc * 4]) =
                    *reinterpret_cast<const float4*>(&Vs[kk][j * 16 + cc * 4]);
            }
#pragma unroll
            for (int ri = 0; ri < 2; ++ri) {
                const float p = __expf(P[rs + 32 * ri][kk ^ (rs & 7)] - m[ri]);
                l[ri] += p;
#pragma unroll
                for (int i = 0; i < 16; ++i) o[ri][i] = fmaf(p, vf[i], o[ri][i]);
            }
        }
        __syncthreads();
    }

#pragma unroll
    for (int ri = 0; ri < 2; ++ri) {
        const float inv = 1.0f / l[ri];
        float* dst = Ob + (size_t)(q0 + rs + 32 * ri) * DIM + j * 16;
#pragma unroll
        for (int i = 0; i < 16; i += 4) {
            float4 v4;
            v4.x = o[ri][i + 0] * inv;
            v4.y = o[ri][i + 1] * inv;
            v4.z = o[ri][i + 2] * inv;
            v4.w = o[ri][i + 3] * inv;
            *reinterpret_cast<float4*>(dst + i) = v4;
        }
    }
}

// ---------------------------------------------------------------------------
// Workspace layout (floats): Q | K | V | attn_out, each 4096*2048 (32 MiB).
// ---------------------------------------------------------------------------
extern "C" void kernel_launch(void* const* d_in, const int* in_sizes, int n_in,
                              void* d_out, int out_size, void* d_ws, size_t ws_size,
                              hipStream_t stream) {
    const float* x  = (const float*)d_in[0];
    const float* Wq = (const float*)d_in[1];
    const float* Wk = (const float*)d_in[2];
    const float* Wv = (const float*)d_in[3];
    const float* Wo = (const float*)d_in[4];
    float* out = (float*)d_out;

    const size_t mat = (size_t)MROWS * DIM;
    float* Qw = (float*)d_ws;
    float* Kw = Qw + mat;
    float* Vw = Kw + mat;
    float* Aw = Vw + mat;

    const dim3 blk(256);
    const dim3 ggrid(DIM / 128, MROWS / 128);
    gemm_f32<<<ggrid, blk, 0, stream>>>(x, Wq, Qw, MROWS, DIM, DIM);
    gemm_f32<<<ggrid, blk, 0, stream>>>(x, Wk, Kw, MROWS, DIM, DIM);
    gemm_f32<<<ggrid, blk, 0, stream>>>(x, Wv, Vw, MROWS, DIM, DIM);

    const dim3 agrid((SEQ / QT) * HEADS * BATCH);  // 1024 blocks, heavy-first remap inside
    attn_f32<<<agrid, blk, 0, stream>>>(Qw, Kw, Vw, Aw);

    gemm_f32<<<ggrid, blk, 0, stream>>>(Aw, Wo, out, MROWS, DIM, DIM);
}